// Round 1
// baseline (56.767 us; speedup 1.0000x reference)
//
#include <hip/hip_runtime.h>

#define Bb 4
#define Ss 512
#define Dd 512
#define Rr 64
#define DR (Dd * Rr)            // 32768 rows of U1
#define NCH 32                  // y-chunks for partial mean
#define YPER (Ss / NCH)         // 16

// ---------------- K1: partial sums over y for h_backward mean ----------------
__global__ __launch_bounds__(512) void k1_partial(const float* __restrict__ hb,
                                                  float* __restrict__ part) {
    int b  = blockIdx.x >> 5;          // /NCH
    int ch = blockIdx.x & 31;
    int j  = threadIdx.x;              // 0..511
    const float* p = hb + ((size_t)(b * Ss) + ch * YPER) * Dd + j;
    float acc = 0.f;
    #pragma unroll
    for (int y = 0; y < YPER; ++y) acc += p[(size_t)y * Dd];
    part[(size_t)blockIdx.x * Dd + j] = acc;   // part[(b*NCH+ch)*D + j]
}

// ---------------- K2a: finalize hbar = mean_y hb ----------------
__global__ __launch_bounds__(256) void k2a_hbar(const float* __restrict__ part,
                                                float* __restrict__ hbar) {
    int idx = blockIdx.x * 256 + threadIdx.x;  // 0..2047  (b*512 + j)
    int b = idx >> 9;
    int j = idx & 511;
    const float* p = part + (size_t)(b * NCH) * Dd + j;
    float acc = 0.f;
    #pragma unroll
    for (int ch = 0; ch < NCH; ++ch) acc += p[(size_t)ch * Dd];
    hbar[idx] = acc * (1.0f / Ss);
}

// ---------------- K2b: c[b,r] = bias[r] + sum_j hbar[b,j] * U2[D+j, r] -------
__global__ __launch_bounds__(64) void k2b_c(const float* __restrict__ hbar,
                                            const float* __restrict__ U2,
                                            const float* __restrict__ bias,
                                            float* __restrict__ cvec) {
    int b = blockIdx.x, r = threadIdx.x;
    float acc = bias[r];
    const float* u = U2 + (size_t)Dd * Rr + r;    // lower half of U2
    const float* h = hbar + (size_t)b * Dd;
    for (int j = 0; j < Dd; ++j)
        acc = fmaf(h[j], u[(size_t)j * Rr], acc);
    cvec[b * Rr + r] = acc;
}

// ---------------- K2: W'[b,row] = sum_j U1[row,j]*hbar[b,j] + U2[row] --------
// One wave per row (2KB contiguous), 4 rows per wave, hbar in registers.
__global__ __launch_bounds__(256) void k2_w(const float* __restrict__ U1,
                                            const float* __restrict__ U2,
                                            const float* __restrict__ hbar,
                                            float* __restrict__ Wp) {
    int lane = threadIdx.x & 63;
    int wid  = (blockIdx.x << 2) | (threadIdx.x >> 6);  // 0..8191
    // each lane owns j in {lane*4+e + k*256 : e<4, k<2}; preload hbar for 4 b's
    float4 h[Bb][2];
    #pragma unroll
    for (int b = 0; b < Bb; ++b) {
        #pragma unroll
        for (int k = 0; k < 2; ++k)
            h[b][k] = *(const float4*)(hbar + b * Dd + k * 256 + lane * 4);
    }
    #pragma unroll
    for (int q = 0; q < 4; ++q) {
        int row = (wid << 2) | q;                        // 0..32767
        const float4* pu = (const float4*)(U1 + (size_t)row * Dd) + lane;
        float4 u0 = pu[0];
        float4 u1 = pu[64];
        float a[Bb];
        #pragma unroll
        for (int b = 0; b < Bb; ++b) {
            a[b] = u0.x * h[b][0].x + u0.y * h[b][0].y +
                   u0.z * h[b][0].z + u0.w * h[b][0].w +
                   u1.x * h[b][1].x + u1.y * h[b][1].y +
                   u1.z * h[b][1].z + u1.w * h[b][1].w;
        }
        #pragma unroll
        for (int m = 1; m < 64; m <<= 1) {
            #pragma unroll
            for (int b = 0; b < Bb; ++b)
                a[b] += __shfl_xor(a[b], m, 64);
        }
        if (lane == 0) {
            float u2v = U2[row];        // U2[:D] flattened == U2[row]
            #pragma unroll
            for (int b = 0; b < Bb; ++b)
                Wp[(size_t)b * DR + row] = a[b] + u2v;
        }
    }
}

// ---------------- K3: out[b,x,r] = sum_i hf[b,x,i]*W'[b,i,r] + c[b,r] --------
// block = 256 thr = 4 waves; wave -> one x, lanes -> r. 512 blocks.
__global__ __launch_bounds__(256) void k3_out(const float* __restrict__ hf,
                                              const float* __restrict__ Wp,
                                              const float* __restrict__ cvec,
                                              float* __restrict__ out) {
    int r   = threadIdx.x & 63;
    int xq  = threadIdx.x >> 6;          // 0..3 (wave-uniform)
    int bid = blockIdx.x;                // 0..511
    int b   = bid >> 7;
    int x   = ((bid & 127) << 2) | xq;
    const float* w  = Wp + (size_t)b * DR + r;
    const float* hv = hf + ((size_t)(b * Ss) + x) * Dd;
    float acc = 0.f;
    #pragma unroll 8
    for (int i = 0; i < Dd; ++i)
        acc = fmaf(hv[i], w[(size_t)i * Rr], acc);
    out[((size_t)(b * Ss) + x) * Rr + r] = acc + cvec[b * Rr + r];
}

extern "C" void kernel_launch(void* const* d_in, const int* in_sizes, int n_in,
                              void* d_out, int out_size, void* d_ws, size_t ws_size,
                              hipStream_t stream) {
    const float* hf   = (const float*)d_in[0];   // [B,S,D]
    const float* hb   = (const float*)d_in[1];   // [B,S,D]
    const float* U1   = (const float*)d_in[2];   // [D,R,D]
    const float* U2   = (const float*)d_in[3];   // [2D,R]
    const float* bias = (const float*)d_in[4];   // [R]
    float* out = (float*)d_out;                  // [B,S,R]

    float* ws   = (float*)d_ws;
    float* part = ws;                            // B*NCH*D = 65536 floats
    float* hbar = part + (size_t)Bb * NCH * Dd;  // B*D     = 2048
    float* cvec = hbar + (size_t)Bb * Dd;        // B*R     = 256
    float* Wp   = cvec + (size_t)Bb * Rr;        // B*D*R   = 131072

    k1_partial<<<Bb * NCH, 512, 0, stream>>>(hb, part);
    k2a_hbar<<<(Bb * Dd) / 256, 256, 0, stream>>>(part, hbar);
    k2b_c<<<Bb, 64, 0, stream>>>(hbar, U2, bias, cvec);
    k2_w<<<2048, 256, 0, stream>>>(U1, U2, hbar, Wp);
    k3_out<<<512, 256, 0, stream>>>(hf, Wp, cvec, out);
}

// Round 2
// 40.395 us; speedup vs baseline: 1.4053x; 1.4053x over previous
//
#include <hip/hip_runtime.h>

#define Bb 4
#define Ss 512
#define Dd 512
#define Rr 64
#define DR (Dd * Rr)            // 32768 rows of U1
#define NCH 32                  // y-chunks for partial mean
#define YPER (Ss / NCH)         // 16

// ---------------- K1: partial sums over y for h_backward mean ----------------
__global__ __launch_bounds__(512) void k1_partial(const float* __restrict__ hb,
                                                  float* __restrict__ part) {
    int b  = blockIdx.x >> 5;          // /NCH
    int ch = blockIdx.x & 31;
    int j  = threadIdx.x;              // 0..511
    const float* p = hb + ((size_t)(b * Ss) + ch * YPER) * Dd + j;
    float acc = 0.f;
    #pragma unroll
    for (int y = 0; y < YPER; ++y) acc += p[(size_t)y * Dd];
    part[(size_t)blockIdx.x * Dd + j] = acc;   // part[(b*NCH+ch)*D + j]
}

// ---------------- K2a: finalize hbar = mean_y hb ----------------
__global__ __launch_bounds__(256) void k2a_hbar(const float* __restrict__ part,
                                                float* __restrict__ hbar) {
    int idx = blockIdx.x * 256 + threadIdx.x;  // 0..2047  (b*512 + j)
    const float* p = part + ((size_t)(idx >> 9) * NCH) * Dd + (idx & 511);
    float acc = 0.f;
    #pragma unroll
    for (int ch = 0; ch < NCH; ++ch) acc += p[(size_t)ch * Dd];
    hbar[idx] = acc * (1.0f / Ss);
}

// ---------------- K2: W'[b,row] = sum_j U1[row,j]*hbar[b,j] + U2[row] --------
// blocks 0..2047: Wp rows (one wave per 4 rows, butterfly reduce).
// blocks 2048..2051: cvec[b,r] = bias[r] + sum_j hbar[b,j]*U2[D+j,r]
__global__ __launch_bounds__(256) void k2_w(const float* __restrict__ U1,
                                            const float* __restrict__ U2,
                                            const float* __restrict__ bias,
                                            const float* __restrict__ hbar,
                                            float* __restrict__ Wp,
                                            float* __restrict__ cvec) {
    __shared__ float red[4][64];
    if (blockIdx.x >= 2048) {
        int b = blockIdx.x - 2048;
        int r = threadIdx.x & 63, g = threadIdx.x >> 6;
        const float* h = hbar + b * Dd + g * 128;
        const float* u = U2 + (size_t)(Dd + g * 128) * Rr + r;
        float acc = 0.f;
        #pragma unroll 8
        for (int j = 0; j < 128; ++j)
            acc = fmaf(h[j], u[(size_t)j * Rr], acc);
        red[g][r] = acc;
        __syncthreads();
        if (g == 0)
            cvec[(b << 6) + r] = red[0][r] + red[1][r] + red[2][r] + red[3][r] + bias[r];
        return;
    }
    int lane = threadIdx.x & 63;
    int wid  = (blockIdx.x << 2) | (threadIdx.x >> 6);  // 0..8191
    float4 h[Bb][2];
    #pragma unroll
    for (int b = 0; b < Bb; ++b) {
        #pragma unroll
        for (int k = 0; k < 2; ++k)
            h[b][k] = *(const float4*)(hbar + b * Dd + k * 256 + lane * 4);
    }
    #pragma unroll
    for (int q = 0; q < 4; ++q) {
        int row = (wid << 2) | q;                        // 0..32767
        const float4* pu = (const float4*)(U1 + (size_t)row * Dd) + lane;
        float4 u0 = pu[0];
        float4 u1 = pu[64];
        float a[Bb];
        #pragma unroll
        for (int b = 0; b < Bb; ++b) {
            a[b] = u0.x * h[b][0].x + u0.y * h[b][0].y +
                   u0.z * h[b][0].z + u0.w * h[b][0].w +
                   u1.x * h[b][1].x + u1.y * h[b][1].y +
                   u1.z * h[b][1].z + u1.w * h[b][1].w;
        }
        #pragma unroll
        for (int m = 1; m < 64; m <<= 1) {
            #pragma unroll
            for (int b = 0; b < Bb; ++b)
                a[b] += __shfl_xor(a[b], m, 64);
        }
        if (lane == 0) {
            float u2v = U2[row];
            #pragma unroll
            for (int b = 0; b < Bb; ++b)
                Wp[(size_t)b * DR + row] = a[b] + u2v;
        }
    }
}

// ---------------- K3a: partial GEMV with 4-way x-reuse and 4-way i-split -----
// grid 512: (b, xg 0..31, ic 0..3); block 256 = 4 waves; wave: 4 x's, lanes=r.
__global__ __launch_bounds__(256) void k3a(const float* __restrict__ hf,
                                           const float* __restrict__ Wp,
                                           float* __restrict__ part3) {
    int t   = threadIdx.x;
    int r   = t & 63;
    int wv  = t >> 6;                  // 0..3
    int bid = blockIdx.x;              // 0..511
    int b   = bid >> 7;
    int rem = bid & 127;
    int xg  = rem >> 2;                // 0..31
    int ic  = rem & 3;                 // 0..3
    int x0  = xg * 16 + wv * 4;
    int i0  = ic * 128;
    const float* wp = Wp + (size_t)b * DR + (size_t)i0 * Rr + r;
    const float* hp = hf + ((size_t)(b * Ss + x0)) * Dd + i0;
    float a0 = 0.f, a1 = 0.f, a2 = 0.f, a3 = 0.f;
    #pragma unroll 4
    for (int i = 0; i < 128; ++i) {
        float w = wp[(size_t)i * Rr];
        a0 = fmaf(hp[i],          w, a0);
        a1 = fmaf(hp[Dd + i],     w, a1);
        a2 = fmaf(hp[2 * Dd + i], w, a2);
        a3 = fmaf(hp[3 * Dd + i], w, a3);
    }
    float* pp = part3 + ((size_t)(ic * Bb + b) * Ss + x0) * Rr + r;
    pp[0 * Rr] = a0;
    pp[1 * Rr] = a1;
    pp[2 * Rr] = a2;
    pp[3 * Rr] = a3;
}

// ---------------- K3b: combine 4 partials + cvec -> out ----------------------
__global__ __launch_bounds__(256) void k3b(const float* __restrict__ part3,
                                           const float* __restrict__ cvec,
                                           float* __restrict__ out) {
    int idx = blockIdx.x * 256 + threadIdx.x;   // < B*S*R = 131072
    int b = idx >> 15;                          // / (S*R)
    int r = idx & 63;
    const size_t STR = (size_t)Bb * Ss * Rr;    // 131072
    out[idx] = part3[idx] + part3[STR + idx] + part3[2 * STR + idx] +
               part3[3 * STR + idx] + cvec[(b << 6) + r];
}

extern "C" void kernel_launch(void* const* d_in, const int* in_sizes, int n_in,
                              void* d_out, int out_size, void* d_ws, size_t ws_size,
                              hipStream_t stream) {
    const float* hf   = (const float*)d_in[0];   // [B,S,D]
    const float* hb   = (const float*)d_in[1];   // [B,S,D]
    const float* U1   = (const float*)d_in[2];   // [D,R,D]
    const float* U2   = (const float*)d_in[3];   // [2D,R]
    const float* bias = (const float*)d_in[4];   // [R]
    float* out = (float*)d_out;                  // [B,S,R]

    float* ws    = (float*)d_ws;
    float* part  = ws;                             // B*NCH*D = 65536
    float* hbar  = part  + (size_t)Bb * NCH * Dd;  // B*D     = 2048
    float* cvec  = hbar  + (size_t)Bb * Dd;        // B*R     = 256
    float* Wp    = cvec  + (size_t)Bb * Rr;        // B*D*R   = 131072
    float* part3 = Wp    + (size_t)Bb * DR;        // 4*B*S*R = 524288

    k1_partial<<<Bb * NCH, 512, 0, stream>>>(hb, part);
    k2a_hbar<<<(Bb * Dd) / 256, 256, 0, stream>>>(part, hbar);
    k2_w<<<2052, 256, 0, stream>>>(U1, U2, bias, hbar, Wp, cvec);
    k3a<<<512, 256, 0, stream>>>(hf, Wp, part3);
    k3b<<<512, 256, 0, stream>>>(part3, cvec, out);
}

// Round 3
// 40.288 us; speedup vs baseline: 1.4090x; 1.0027x over previous
//
#include <hip/hip_runtime.h>

#define Bb 4
#define Ss 512
#define Dd 512
#define Rr 64
#define DR (Dd * Rr)            // 32768 rows of U1
#define NCH 32                  // y-chunks for partial mean
#define YPER (Ss / NCH)         // 16

// ---------------- K1: partial sums over y for h_backward mean ----------------
__global__ __launch_bounds__(512) void k1_partial(const float* __restrict__ hb,
                                                  float* __restrict__ part) {
    int b  = blockIdx.x >> 5;          // /NCH
    int ch = blockIdx.x & 31;
    int j  = threadIdx.x;              // 0..511
    const float* p = hb + ((size_t)(b * Ss) + ch * YPER) * Dd + j;
    float acc = 0.f;
    #pragma unroll
    for (int y = 0; y < YPER; ++y) acc += p[(size_t)y * Dd];
    part[(size_t)blockIdx.x * Dd + j] = acc;   // part[(b*NCH+ch)*D + j]
}

// ---------------- K2a: finalize hbar = mean_y hb ----------------
__global__ __launch_bounds__(256) void k2a_hbar(const float* __restrict__ part,
                                                float* __restrict__ hbar) {
    int idx = blockIdx.x * 256 + threadIdx.x;  // 0..2047  (b*512 + j)
    const float* p = part + ((size_t)(idx >> 9) * NCH) * Dd + (idx & 511);
    float acc = 0.f;
    #pragma unroll
    for (int ch = 0; ch < NCH; ++ch) acc += p[(size_t)ch * Dd];
    hbar[idx] = acc * (1.0f / Ss);
}

// ---------------- K2: W'[b,row] = sum_j U1[row,j]*hbar[b,j] + U2[row] --------
// blocks 0..2047: Wp rows. One wave -> 4 rows; all 8 U1 loads pre-issued;
// cross-lane reduce = 3 pair-merge shfls (batch b lands on lane b mod 4)
// + 4 butterfly shfls. 7 shfls/row vs 24 before.
// blocks 2048..2051: cvec[b,r] = bias[r] + sum_j hbar[b,j]*U2[D+j,r]
__global__ __launch_bounds__(256) void k2_w(const float* __restrict__ U1,
                                            const float* __restrict__ U2,
                                            const float* __restrict__ bias,
                                            const float* __restrict__ hbar,
                                            float* __restrict__ Wp,
                                            float* __restrict__ cvec) {
    __shared__ float red[4][64];
    if (blockIdx.x >= 2048) {
        int b = blockIdx.x - 2048;
        int r = threadIdx.x & 63, g = threadIdx.x >> 6;
        const float* h = hbar + b * Dd + g * 128;
        const float* u = U2 + (size_t)(Dd + g * 128) * Rr + r;
        float acc = 0.f;
        #pragma unroll 8
        for (int j = 0; j < 128; ++j)
            acc = fmaf(h[j], u[(size_t)j * Rr], acc);
        red[g][r] = acc;
        __syncthreads();
        if (g == 0)
            cvec[(b << 6) + r] = red[0][r] + red[1][r] + red[2][r] + red[3][r] + bias[r];
        return;
    }
    int lane = threadIdx.x & 63;
    int wid  = (blockIdx.x << 2) | (threadIdx.x >> 6);  // 0..8191
    int lm1  = lane & 1, lm2 = lane & 2;

    float4 h[Bb][2];
    #pragma unroll
    for (int b = 0; b < Bb; ++b) {
        #pragma unroll
        for (int k = 0; k < 2; ++k)
            h[b][k] = *(const float4*)(hbar + b * Dd + k * 256 + lane * 4);
    }
    // pre-issue all 8 U1 loads (8KB/wave in flight)
    const float4* pu = (const float4*)(U1 + ((size_t)wid << 2) * Dd) + lane;
    float4 uu[8];
    #pragma unroll
    for (int q = 0; q < 4; ++q) {
        uu[2 * q]     = pu[q * 128];
        uu[2 * q + 1] = pu[q * 128 + 64];
    }
    #pragma unroll
    for (int q = 0; q < 4; ++q) {
        int row = (wid << 2) | q;                        // 0..32767
        float4 u0 = uu[2 * q], u1 = uu[2 * q + 1];
        float a[4];
        #pragma unroll
        for (int b = 0; b < Bb; ++b) {
            a[b] = u0.x * h[b][0].x + u0.y * h[b][0].y +
                   u0.z * h[b][0].z + u0.w * h[b][0].w +
                   u1.x * h[b][1].x + u1.y * h[b][1].y +
                   u1.z * h[b][1].z + u1.w * h[b][1].w;
        }
        // pair-merge: after these 3 shfls, lane holds batch (lane&3) partial
        float snd, rcv, s01, s23, t;
        snd = lm1 ? a[0] : a[1];
        rcv = __shfl_xor(snd, 1, 64);
        s01 = (lm1 ? a[1] : a[0]) + rcv;
        snd = lm1 ? a[2] : a[3];
        rcv = __shfl_xor(snd, 1, 64);
        s23 = (lm1 ? a[3] : a[2]) + rcv;
        snd = lm2 ? s01 : s23;
        rcv = __shfl_xor(snd, 2, 64);
        t   = (lm2 ? s23 : s01) + rcv;
        // butterfly over remaining lane bits
        t += __shfl_xor(t, 4, 64);
        t += __shfl_xor(t, 8, 64);
        t += __shfl_xor(t, 16, 64);
        t += __shfl_xor(t, 32, 64);
        if (lane < 4)
            Wp[(size_t)lane * DR + row] = t + U2[row];
    }
}

// ---------------- K3a: partial GEMV, 4-way x-reuse, 4-way i-split ------------
// grid 512: (b, xg 0..31, ic 0..3); block 256 = 4 waves; wave: 4 x's, lanes=r.
// hf loaded as broadcast float4 (1 instr / 4 i / x) instead of 4 scalars.
__global__ __launch_bounds__(256) void k3a(const float* __restrict__ hf,
                                           const float* __restrict__ Wp,
                                           float* __restrict__ part3) {
    int t   = threadIdx.x;
    int r   = t & 63;
    int wv  = t >> 6;                  // 0..3
    int bid = blockIdx.x;              // 0..511
    int b   = bid >> 7;
    int rem = bid & 127;
    int xg  = rem >> 2;                // 0..31
    int ic  = rem & 3;                 // 0..3
    int x0  = xg * 16 + wv * 4;
    int i0  = ic * 128;
    const float* wp = Wp + (size_t)b * DR + (size_t)i0 * Rr + r;
    const float* hp = hf + ((size_t)(b * Ss + x0)) * Dd + i0;
    float a0 = 0.f, a1 = 0.f, a2 = 0.f, a3 = 0.f;
    #pragma unroll 4
    for (int c = 0; c < 32; ++c) {
        float wA = wp[(size_t)(4 * c + 0) * Rr];
        float wB = wp[(size_t)(4 * c + 1) * Rr];
        float wC = wp[(size_t)(4 * c + 2) * Rr];
        float wD = wp[(size_t)(4 * c + 3) * Rr];
        float4 h0 = *(const float4*)(hp + 4 * c);
        float4 h1 = *(const float4*)(hp + Dd + 4 * c);
        float4 h2 = *(const float4*)(hp + 2 * Dd + 4 * c);
        float4 h3 = *(const float4*)(hp + 3 * Dd + 4 * c);
        a0 = fmaf(h0.x, wA, a0); a0 = fmaf(h0.y, wB, a0);
        a0 = fmaf(h0.z, wC, a0); a0 = fmaf(h0.w, wD, a0);
        a1 = fmaf(h1.x, wA, a1); a1 = fmaf(h1.y, wB, a1);
        a1 = fmaf(h1.z, wC, a1); a1 = fmaf(h1.w, wD, a1);
        a2 = fmaf(h2.x, wA, a2); a2 = fmaf(h2.y, wB, a2);
        a2 = fmaf(h2.z, wC, a2); a2 = fmaf(h2.w, wD, a2);
        a3 = fmaf(h3.x, wA, a3); a3 = fmaf(h3.y, wB, a3);
        a3 = fmaf(h3.z, wC, a3); a3 = fmaf(h3.w, wD, a3);
    }
    float* pp = part3 + ((size_t)(ic * Bb + b) * Ss + x0) * Rr + r;
    pp[0 * Rr] = a0;
    pp[1 * Rr] = a1;
    pp[2 * Rr] = a2;
    pp[3 * Rr] = a3;
}

// ---------------- K3b: combine 4 partials + cvec -> out ----------------------
__global__ __launch_bounds__(256) void k3b(const float* __restrict__ part3,
                                           const float* __restrict__ cvec,
                                           float* __restrict__ out) {
    int idx = blockIdx.x * 256 + threadIdx.x;   // < B*S*R = 131072
    int b = idx >> 15;                          // / (S*R)
    int r = idx & 63;
    const size_t STR = (size_t)Bb * Ss * Rr;    // 131072
    out[idx] = part3[idx] + part3[STR + idx] + part3[2 * STR + idx] +
               part3[3 * STR + idx] + cvec[(b << 6) + r];
}

extern "C" void kernel_launch(void* const* d_in, const int* in_sizes, int n_in,
                              void* d_out, int out_size, void* d_ws, size_t ws_size,
                              hipStream_t stream) {
    const float* hf   = (const float*)d_in[0];   // [B,S,D]
    const float* hb   = (const float*)d_in[1];   // [B,S,D]
    const float* U1   = (const float*)d_in[2];   // [D,R,D]
    const float* U2   = (const float*)d_in[3];   // [2D,R]
    const float* bias = (const float*)d_in[4];   // [R]
    float* out = (float*)d_out;                  // [B,S,R]

    float* ws    = (float*)d_ws;
    float* part  = ws;                             // B*NCH*D = 65536
    float* hbar  = part  + (size_t)Bb * NCH * Dd;  // B*D     = 2048
    float* cvec  = hbar  + (size_t)Bb * Dd;        // B*R     = 256
    float* Wp    = cvec  + (size_t)Bb * Rr;        // B*D*R   = 131072
    float* part3 = Wp    + (size_t)Bb * DR;        // 4*B*S*R = 524288

    k1_partial<<<Bb * NCH, 512, 0, stream>>>(hb, part);
    k2a_hbar<<<(Bb * Dd) / 256, 256, 0, stream>>>(part, hbar);
    k2_w<<<2052, 256, 0, stream>>>(U1, U2, bias, hbar, Wp, cvec);
    k3a<<<512, 256, 0, stream>>>(hf, Wp, part3);
    k3b<<<512, 256, 0, stream>>>(part3, cvec, out);
}